// Round 2
// baseline (112.777 us; speedup 1.0000x reference)
//
#include <hip/hip_runtime.h>

// Problem constants (fixed by setup_inputs): N=2048, d=256, T=256, Q=64
#define NN   2048
#define DD   256
#define TT   256
#define NYC  16384           // T*Q flattened y columns
#define NCHUNK_XY 64         // 16384 / 256 cols per chunk
#define NCHUNK_XX 8          // 2048 / 256
#define CHUNK_COLS 256

static constexpr float INV_TEMP = 1.0f / 0.3f;

typedef __bf16 bf16x8 __attribute__((ext_vector_type(8)));
typedef float  f32x4  __attribute__((ext_vector_type(4)));

// Frag-linear layout: for a matrix M[C][256] (bf16), fragment index
// j = (g*8 + ks)*64 + lane holds M[g*16 + (lane&15)][ks*32 + (lane>>4)*8 .. +7].
// This makes every wave's MFMA operand load a contiguous 1 KB global read,
// and the SAME layout serves both the A side and the B side of
// mfma_f32_16x16x32_bf16 (row = lane&15, k-slice = lane>>4).

// ------------------------------------------------ convert + zero accumulators
// Thread->fragment remap: 4 consecutive threads cover the 4 k-quads (q=0..3)
// of ONE column, so global reads are 128 B-contiguous per thread-quad; the
// frag-linear write is a dense permutation of a 1 KB block per wave (coalesced).
__global__ void cvt_zero_kernel(const float* __restrict__ x, const float* __restrict__ y,
                                bf16x8* __restrict__ xfl, bf16x8* __restrict__ yfl,
                                float* __restrict__ acc /* 3*NN floats: Tot,Pxy,Pxx */) {
    const int tid0   = blockIdx.x * blockDim.x + threadIdx.x;
    const int stride = gridDim.x * blockDim.x;
    for (int j = tid0; j < 3 * NN; j += stride) acc[j] = 0.f;

    const int NXF = NN * DD / 8;          // 65536 x-fragments
    for (int j = tid0; j < NXF; j += stride) {
        const int gk  = j >> 6;           // g*8 + ks
        const int sub = j & 63;
        const int qq  = sub & 3;          // k-quad (lane>>4 in fragment space)
        const int cc  = (sub >> 2) & 15;  // col-within-16 (lane&15)
        const int col = ((gk >> 3) << 4) + cc;
        const int k0  = ((gk & 7) << 5) + (qq << 3);
        const float4* s = (const float4*)(x + (size_t)col * DD + k0);
        float4 v0 = s[0], v1 = s[1];
        bf16x8 o;
        o[0] = (__bf16)v0.x; o[1] = (__bf16)v0.y; o[2] = (__bf16)v0.z; o[3] = (__bf16)v0.w;
        o[4] = (__bf16)v1.x; o[5] = (__bf16)v1.y; o[6] = (__bf16)v1.z; o[7] = (__bf16)v1.w;
        xfl[(size_t)gk * 64 + qq * 16 + cc] = o;
    }
    const int NYF = NYC * DD / 8;         // 524288 y-fragments
    for (int j = tid0; j < NYF; j += stride) {
        const int gk  = j >> 6;
        const int sub = j & 63;
        const int qq  = sub & 3;
        const int cc  = (sub >> 2) & 15;
        const int col = ((gk >> 3) << 4) + cc;
        const int k0  = ((gk & 7) << 5) + (qq << 3);
        const float4* s = (const float4*)(y + (size_t)col * DD + k0);
        float4 v0 = s[0], v1 = s[1];
        bf16x8 o;
        o[0] = (__bf16)v0.x; o[1] = (__bf16)v0.y; o[2] = (__bf16)v0.z; o[3] = (__bf16)v0.w;
        o[4] = (__bf16)v1.x; o[5] = (__bf16)v1.y; o[6] = (__bf16)v1.z; o[7] = (__bf16)v1.w;
        yfl[(size_t)gk * 64 + qq * 16 + cc] = o;
    }
}

// ------------------------------------------------ stats (GEMM + exp + grouped sums)
// 1D grid of 576 blocks (XCD-swizzled): decode -> (bx row-block of 256 rows,
// chunk of 256 cols; chunks 0..63 = x@y^T, 64..71 = x@x^T).
// 4 waves/block, each wave owns 64 rows; A panel (64x256) fully in registers.
// No LDS, no barriers: B fragments stream straight from L1/L2 via frag-linear
// coalesced loads, software-pipelined in half-groups (4 ks) ahead of the MFMAs.
// Balance: t=4 row-reuse -> 256 B of B per MFMA = ~64 B/cyc/CU at full MFMA
// rate, right at the measured ~60 B/cyc L1/L2 ceiling.
__global__ __launch_bounds__(256, 2) void stats_kernel(
        const bf16x8* __restrict__ xfl, const bf16x8* __restrict__ yfl,
        const int* __restrict__ tid,
        float* __restrict__ Tot, float* __restrict__ Pxy,
        float* __restrict__ Pxx, float* __restrict__ diag) {
    const int id    = blockIdx.x;
    // XCD swizzle: all 8 row-blocks of a chunk land on the same XCD (id % 8 const).
    const int chunk = (id & 7) + ((id >> 6) << 3);   // 0..71
    const int bx    = (id >> 3) & 7;                 // 0..7
    const int mode  = (chunk >= NCHUNK_XY);          // 0 = x@y^T, 1 = x@x^T
    const int colbase = (mode ? chunk - NCHUNK_XY : chunk) * CHUNK_COLS;
    const bf16x8* __restrict__ colfl = mode ? xfl : yfl;

    const int lane = threadIdx.x & 63;
    const int w    = threadIdx.x >> 6;
    const int c16  = lane & 15;
    const int q    = lane >> 4;
    const int rowbase = bx * 256 + w * 64;
    const int rowg    = rowbase >> 4;                // row16-group index

    // A fragments: 64 rows x K=256 resident in registers (128 VGPRs).
    bf16x8 a[4][8];
#pragma unroll
    for (int t = 0; t < 4; t++)
#pragma unroll
        for (int ks = 0; ks < 8; ks++)
            a[t][ks] = xfl[((size_t)(rowg + t) * 8 + ks) * 64 + lane];

    // Row track-ids packed 4x8-bit (tids < 256) to save VGPRs.
    int trow[4];
#pragma unroll
    for (int t = 0; t < 4; t++) {
        const int rb = rowbase + t * 16 + q * 4;
        trow[t] = tid[rb] | (tid[rb + 1] << 8) | (tid[rb + 2] << 16) | (tid[rb + 3] << 24);
    }

    const bf16x8* bptr = colfl + (size_t)(colbase >> 4) * 8 * 64 + lane;
    const bool wantdiag = mode && (bx == (colbase >> 8));

    float tot[4][4] = {};
    float pos[4][4] = {};

    bf16x8 b0[4], b1[4];
#pragma unroll
    for (int s = 0; s < 4; s++) b0[s] = bptr[(size_t)s * 64];

    for (int ct = 0; ct < 16; ct++) {
        // prefetch second half of this group while first half computes
#pragma unroll
        for (int s = 0; s < 4; s++) b1[s] = bptr[((size_t)ct * 8 + 4 + s) * 64];
        const int col    = colbase + ct * 16 + c16;
        const int coltid = mode ? tid[col] : (col & (TT - 1));

        f32x4 acc[4];
#pragma unroll
        for (int t = 0; t < 4; t++) acc[t] = (f32x4){0.f, 0.f, 0.f, 0.f};

#pragma unroll
        for (int s = 0; s < 4; s++)
#pragma unroll
            for (int t = 0; t < 4; t++)
                acc[t] = __builtin_amdgcn_mfma_f32_16x16x32_bf16(a[t][s], b0[s], acc[t], 0, 0, 0);

        if (ct < 15) {      // prefetch next group's first half under b1's MFMAs
#pragma unroll
            for (int s = 0; s < 4; s++) b0[s] = bptr[((size_t)(ct + 1) * 8 + s) * 64];
        }

#pragma unroll
        for (int s = 0; s < 4; s++)
#pragma unroll
            for (int t = 0; t < 4; t++)
                acc[t] = __builtin_amdgcn_mfma_f32_16x16x32_bf16(a[t][4 + s], b1[s], acc[t], 0, 0, 0);

        // epilogue: exp + grouped accumulation (overlaps next b0 loads)
#pragma unroll
        for (int t = 0; t < 4; t++) {
            const int rw0 = rowbase + t * 16 + q * 4;
#pragma unroll
            for (int r = 0; r < 4; r++) {
                const float val = __expf(acc[t][r] * INV_TEMP);
                tot[t][r] += val;
                pos[t][r] += (((trow[t] >> (8 * r)) & 255) == coltid) ? val : 0.f;
                if (wantdiag && col == rw0 + r)
                    diag[col] = val;                 // unique writer per diagonal elem
            }
        }
    }

    // Reduce across the 16 column-lanes sharing (q, r); one atomic per row.
#pragma unroll
    for (int t = 0; t < 4; t++)
#pragma unroll
        for (int r = 0; r < 4; r++) {
            float aS = tot[t][r], p = pos[t][r];
#pragma unroll
            for (int off = 1; off < 16; off <<= 1) {
                aS += __shfl_xor(aS, off);
                p  += __shfl_xor(p, off);
            }
            if (c16 == 0) {
                const int row = rowbase + t * 16 + q * 4 + r;
                atomicAdd(&Tot[row], aS);
                atomicAdd(mode ? &Pxx[row] : &Pxy[row], p);
            }
        }
}

// ------------------------------------------------ finalize (reads 32 KB only)
__global__ void finalize_kernel(const float* __restrict__ Tot, const float* __restrict__ Pxy,
                                const float* __restrict__ Pxx, const float* __restrict__ diag,
                                const int* __restrict__ tid, float* __restrict__ out) {
    __shared__ float num_s[TT], den_s[TT];
    __shared__ int cnt_s[TT];
    const int t = threadIdx.x;  // 256 threads
    num_s[t] = 0.f; den_s[t] = 0.f; cnt_s[t] = 0;
    __syncthreads();
    for (int i = t; i < NN; i += 256) {
        float tt_ = Tot[i], pxy = Pxy[i], pxx = Pxx[i];
        float num = pxy + 0.5f * (pxx - diag[i]);
        float den = tt_ - pxy - pxx;
        int tr = tid[i];
        atomicAdd(&num_s[tr], num);
        atomicAdd(&den_s[tr], den);
        atomicAdd(&cnt_s[tr], 1);
    }
    __syncthreads();
    float lt = 0.f, pr = 0.f;
    if (cnt_s[t] > 0) {
        lt = -logf(num_s[t] / (den_s[t] + num_s[t]));
        pr = 1.f;
    }
    for (int off = 32; off; off >>= 1) { lt += __shfl_down(lt, off); pr += __shfl_down(pr, off); }
    __shared__ float ls[4], ps[4];
    if ((t & 63) == 0) { ls[t >> 6] = lt; ps[t >> 6] = pr; }
    __syncthreads();
    if (t == 0) out[0] = (ls[0] + ls[1] + ls[2] + ls[3]) / (ps[0] + ps[1] + ps[2] + ps[3]);
}

// ------------------------------------------------ launch
extern "C" void kernel_launch(void* const* d_in, const int* in_sizes, int n_in,
                              void* d_out, int out_size, void* d_ws, size_t ws_size,
                              hipStream_t stream) {
    const float* x   = (const float*)d_in[0];
    const int*   tid = (const int*)d_in[1];
    const float* y   = (const float*)d_in[2];
    float* out = (float*)d_out;

    char* ws = (char*)d_ws;
    bf16x8* xfl = (bf16x8*)ws;                       // 1 MB frag-linear x
    bf16x8* yfl = (bf16x8*)(ws + (1u << 20));        // 8 MB frag-linear y
    float* acc  = (float*)(ws + 9u * (1u << 20));    // Tot,Pxy,Pxx,diag: 4*2048 f32
    float* Tot  = acc;
    float* Pxy  = acc + NN;
    float* Pxx  = acc + 2 * NN;
    float* diag = acc + 3 * NN;                      // fully rewritten by stats (mode 1)

    cvt_zero_kernel<<<1024, 256, 0, stream>>>(x, y, xfl, yfl, acc);
    stats_kernel<<<576, 256, 0, stream>>>(xfl, yfl, tid, Tot, Pxy, Pxx, diag);
    finalize_kernel<<<1, 256, 0, stream>>>(Tot, Pxy, Pxx, diag, tid, out);
}